// Round 6
// baseline (197.290 us; speedup 1.0000x reference)
//
#include <hip/hip_runtime.h>
#include <hip/hip_bf16.h>

#define HID   128
#define NPIX  (256*512)
#define L2E2  2.88539008177792681f   // 2*log2(e)

typedef __attribute__((ext_vector_type(8))) short bf16x8;
typedef __attribute__((ext_vector_type(4))) float f32x4;

__device__ inline unsigned pack2(float a, float b) {
    __hip_bfloat16 lo = __float2bfloat16(a);
    __hip_bfloat16 hi = __float2bfloat16(b);
    unsigned short ul = *reinterpret_cast<unsigned short*>(&lo);
    unsigned short uh = *reinterpret_cast<unsigned short*>(&hi);
    return (unsigned)ul | ((unsigned)uh << 16);
}
__device__ inline float ulo(unsigned u) { union { unsigned u; float f; } v; v.u = u << 16;        return v.f; }
__device__ inline float uhi(unsigned u) { union { unsigned u; float f; } v; v.u = u & 0xffff0000u; return v.f; }

// tanh(z) where u = 2*log2e*z already folded into operands
__device__ inline float actf(float u) {
    float e = exp2f(u);
    return 1.0f - 2.0f * __builtin_amdgcn_rcpf(e + 1.0f);
}

__device__ inline bf16x8 bc(uint4 v) { return __builtin_bit_cast(bf16x8, v); }

__device__ __forceinline__ uint2 quadact(f32x4 a, uint2 rec, float4 bet) {
    float v0 = actf(fmaf(bet.x, ulo(rec.x), a[0]));
    float v1 = actf(fmaf(bet.y, uhi(rec.x), a[1]));
    float v2 = actf(fmaf(bet.z, ulo(rec.y), a[2]));
    float v3 = actf(fmaf(bet.w, uhi(rec.y), a[3]));
    return make_uint2(pack2(v0, v1), pack2(v2, v3));
}

// ---- prologue: W_h / W_out -> frag-ordered bf16 in ws, rows pre-scaled by 2log2e*resp ----
// chunk# = (lay*8 + rt)*4 + kb ; lane slot l holds
//   Wh[lay][rt*16+(l&15)][kb*32+(l>>4)*8 ..+8] * (L2E2*resp[lay+1][row])
// W_out chunks (16-row zero-padded, scaled by L2E2*resp_out) at uint4 offset 4096.
__global__ __launch_bounds__(256) void prep_weights(
    const float* __restrict__ W_h, const float* __restrict__ W_out,
    const float* __restrict__ resp, const float* __restrict__ resp_out,
    unsigned short* __restrict__ ws)
{
    int c = blockIdx.x * 256 + threadIdx.x;
    if (c < 4096) {
        int l = c & 63, kb = (c >> 6) & 3, rt = (c >> 8) & 7, lay = (c >> 11) & 1;
        int row = rt * 16 + (l & 15);
        int k   = kb * 32 + (l >> 4) * 8;
        float al = L2E2 * resp[(lay + 1) * HID + row];
        const float* src = W_h + (lay * HID + row) * HID + k;
        float4 f0 = *(const float4*)src, f1 = *(const float4*)(src + 4);
        uint4 v;
        v.x = pack2(al * f0.x, al * f0.y); v.y = pack2(al * f0.z, al * f0.w);
        v.z = pack2(al * f1.x, al * f1.y); v.w = pack2(al * f1.z, al * f1.w);
        *(uint4*)(ws + (size_t)c * 8) = v;
    } else if (c < 4352) {
        int c2 = c - 4096, l = c2 & 63, kb = c2 >> 6;
        int row = l & 15, k = kb * 32 + (l >> 4) * 8;
        uint4 v = {0u, 0u, 0u, 0u};
        if (row < 3) {
            float al = L2E2 * resp_out[row];
            const float* src = W_out + row * HID + k;
            float4 f0 = *(const float4*)src, f1 = *(const float4*)(src + 4);
            v.x = pack2(al * f0.x, al * f0.y); v.y = pack2(al * f0.z, al * f0.w);
            v.z = pack2(al * f1.x, al * f1.y); v.w = pack2(al * f1.z, al * f1.w);
        }
        *(uint4*)(ws + 32768 + (size_t)c2 * 8) = v;
    }
}

// 8 waves per block, each wave owns 16 pixels end-to-end. One barrier (after W
// staging), then waves are fully independent: no cross-wave data, no syncs.
__global__ __launch_bounds__(512) void fused_net(
    const float* __restrict__ x_in,     // [3][NPIX]
    const float* __restrict__ W_in,     // [128][3]
    const float* __restrict__ r_rec,    // [3][128]
    const float* __restrict__ resp,     // [3][128]
    const float* __restrict__ bias,     // [3][128]
    const float* __restrict__ b_out,    // [3]
    const int*   __restrict__ n_iters_p,
    const unsigned short* __restrict__ wsw,
    float* __restrict__ out)            // [3][NPIX]
{
    __shared__ __align__(16) uint4 Wh_lds[4096];               // 65536 B (both layers)
    __shared__ __align__(16) unsigned short plane[8][2048];    // 32768 B: 4KB/wave private
    __shared__ float4 Winp_s[HID];      // {a*w0,a*w1,a*w2,gamma0}, a = L2E2*resp0
    __shared__ float  beta_s[3 * HID];  // L2E2*resp*r_rec
    __shared__ float  gamma_s[2 * HID]; // L2E2*bias, layers 1,2
    __shared__ float  gammao_s[16];     // L2E2*b_out, zero-padded
    __shared__ float  xs[3 * 128];

    const int t = threadIdx.x;
    const int w = t >> 6, l = t & 63;
    const int lr = l & 15, lg = l >> 4;
    const int niters = *n_iters_p;
    const uint4* wsU = (const uint4*)wsw;

    // ---- stage W + params (once per block), single barrier ----
    #pragma unroll
    for (int i = 0; i < 8; ++i) Wh_lds[t + i * 512] = wsU[t + i * 512];
    if (t < 3 * HID) beta_s[t] = L2E2 * resp[t] * r_rec[t];
    if (t < 2 * HID) gamma_s[t] = L2E2 * bias[HID + t];
    if (t < HID) {
        float a = L2E2 * resp[t];
        float4 pv;
        pv.x = a * W_in[t * 3 + 0];
        pv.y = a * W_in[t * 3 + 1];
        pv.z = a * W_in[t * 3 + 2];
        pv.w = L2E2 * bias[t];
        Winp_s[t] = pv;
    }
    if (t < 16) gammao_s[t] = (t < 3) ? L2E2 * b_out[t] : 0.0f;
    if (t < 3 * 128) xs[t] = x_in[(t >> 7) * NPIX + (int)blockIdx.x * 128 + (t & 127)];
    __syncthreads();
    // ---- no barriers below this line ----

    const int pixb = (int)blockIdx.x * 128 + w * 16;   // wave's 16 pixels: pixb + lr

    // L0 per-lane constants: rows R = kb*32 + lg*8 + j, pixel lr
    const float x0 = xs[w * 16 + lr], x1 = xs[128 + w * 16 + lr], x2 = xs[256 + w * 16 + lr];
    float c1[32], bt0[32];
    #pragma unroll
    for (int kb = 0; kb < 4; ++kb)
        #pragma unroll
        for (int j = 0; j < 8; ++j) {
            int R = kb * 32 + lg * 8 + j;
            float4 wp = Winp_s[R];
            c1[kb * 8 + j]  = fmaf(wp.x, x0, fmaf(wp.y, x1, fmaf(wp.z, x2, wp.w)));
            bt0[kb * 8 + j] = beta_s[R];
        }

    unsigned rec0[16];           // h0 packed == layer-1 B-fragments
    uint2 rec1[8], rec2[8];      // h1/h2 in C-layout (per row-tile)
    #pragma unroll
    for (int i = 0; i < 16; ++i) rec0[i] = 0u;
    #pragma unroll
    for (int i = 0; i < 8; ++i) { rec1[i] = make_uint2(0u, 0u); rec2[i] = make_uint2(0u, 0u); }

    unsigned short* myplane = plane[w];
    const bf16x8* BP = (const bf16x8*)myplane;

    for (int it = 0; it < niters; ++it) {
        // ---- L0: h0 = tanh(c1 + beta0*h0_prev), stays in registers ----
        #pragma unroll
        for (int q = 0; q < 16; ++q) {
            int e = q * 2;
            unsigned rp = rec0[q];
            float v0 = actf(fmaf(bt0[e],     ulo(rp), c1[e]));
            float v1 = actf(fmaf(bt0[e + 1], uhi(rp), c1[e + 1]));
            rec0[q] = pack2(v0, v1);
        }

        // ---- layer 1: B = rec0 (registers), A streamed from LDS, out -> plane + rec1 ----
        {
            uint4 u0 = {rec0[0], rec0[1], rec0[2], rec0[3]};
            uint4 u1 = {rec0[4], rec0[5], rec0[6], rec0[7]};
            uint4 u2 = {rec0[8], rec0[9], rec0[10], rec0[11]};
            uint4 u3 = {rec0[12], rec0[13], rec0[14], rec0[15]};
            bf16x8 b0 = bc(u0), b1 = bc(u1), b2 = bc(u2), b3 = bc(u3);
            #pragma unroll
            for (int rt = 0; rt < 8; ++rt) {
                const uint4* AP = Wh_lds + rt * 256 + l;
                float4 gm = *(const float4*)(gamma_s + rt * 16 + lg * 4);
                f32x4 acc = {gm.x, gm.y, gm.z, gm.w};
                acc = __builtin_amdgcn_mfma_f32_16x16x32_bf16(bc(AP[0]),   b0, acc, 0, 0, 0);
                acc = __builtin_amdgcn_mfma_f32_16x16x32_bf16(bc(AP[64]),  b1, acc, 0, 0, 0);
                acc = __builtin_amdgcn_mfma_f32_16x16x32_bf16(bc(AP[128]), b2, acc, 0, 0, 0);
                acc = __builtin_amdgcn_mfma_f32_16x16x32_bf16(bc(AP[192]), b3, acc, 0, 0, 0);
                float4 bt = *(const float4*)(beta_s + HID + rt * 16 + lg * 4);
                uint2 nv = quadact(acc, rec1[rt], bt);
                rec1[rt] = nv;
                int r0 = rt * 16 + lg * 4;   // rows r0..r0+3, pixel lr -> frag-ordered plane
                *(uint2*)(myplane + ((r0 >> 5) * 512 + ((r0 >> 3) & 3) * 128 + lr * 8 + (r0 & 7))) = nv;
            }
        }

        // ---- layer 2: B = h1 from own plane (in-order DS, no sync), out -> rec2 (+plane on last) ----
        {
            bf16x8 b0 = BP[0 * 64 + l], b1 = BP[1 * 64 + l], b2 = BP[2 * 64 + l], b3 = BP[3 * 64 + l];
            const bool last = (it == niters - 1);
            #pragma unroll
            for (int rt = 0; rt < 8; ++rt) {
                const uint4* AP = Wh_lds + 2048 + rt * 256 + l;
                float4 gm = *(const float4*)(gamma_s + HID + rt * 16 + lg * 4);
                f32x4 acc = {gm.x, gm.y, gm.z, gm.w};
                acc = __builtin_amdgcn_mfma_f32_16x16x32_bf16(bc(AP[0]),   b0, acc, 0, 0, 0);
                acc = __builtin_amdgcn_mfma_f32_16x16x32_bf16(bc(AP[64]),  b1, acc, 0, 0, 0);
                acc = __builtin_amdgcn_mfma_f32_16x16x32_bf16(bc(AP[128]), b2, acc, 0, 0, 0);
                acc = __builtin_amdgcn_mfma_f32_16x16x32_bf16(bc(AP[192]), b3, acc, 0, 0, 0);
                float4 bt = *(const float4*)(beta_s + 2 * HID + rt * 16 + lg * 4);
                uint2 nv = quadact(acc, rec2[rt], bt);
                rec2[rt] = nv;
                if (last) {
                    int r0 = rt * 16 + lg * 4;
                    *(uint2*)(myplane + ((r0 >> 5) * 512 + ((r0 >> 3) & 3) * 128 + lr * 8 + (r0 & 7))) = nv;
                }
            }
        }
    }

    // ---- output layer: wave-local, h2 from own plane, W_out frags from ws (L2-hot) ----
    {
        bf16x8 b0 = BP[0 * 64 + l], b1 = BP[1 * 64 + l], b2 = BP[2 * 64 + l], b3 = BP[3 * 64 + l];
        float4 go = *(const float4*)(gammao_s + lg * 4);
        f32x4 acc = {go.x, go.y, go.z, go.w};
        acc = __builtin_amdgcn_mfma_f32_16x16x32_bf16(bc(wsU[4096 + 0 * 64 + l]), b0, acc, 0, 0, 0);
        acc = __builtin_amdgcn_mfma_f32_16x16x32_bf16(bc(wsU[4096 + 1 * 64 + l]), b1, acc, 0, 0, 0);
        acc = __builtin_amdgcn_mfma_f32_16x16x32_bf16(bc(wsU[4096 + 2 * 64 + l]), b2, acc, 0, 0, 0);
        acc = __builtin_amdgcn_mfma_f32_16x16x32_bf16(bc(wsU[4096 + 3 * 64 + l]), b3, acc, 0, 0, 0);
        int p = pixb + lr;
        if (lg == 0) {
            out[0 * NPIX + p] = actf(acc[0]);
            out[1 * NPIX + p] = actf(acc[1]);
            out[2 * NPIX + p] = actf(acc[2]);
        }
    }
}

extern "C" void kernel_launch(void* const* d_in, const int* in_sizes, int n_in,
                              void* d_out, int out_size, void* d_ws, size_t ws_size,
                              hipStream_t stream) {
    const float* x_in     = (const float*)d_in[0];
    const float* W_in     = (const float*)d_in[1];
    const float* W_h      = (const float*)d_in[2];
    const float* r_rec    = (const float*)d_in[3];
    const float* resp     = (const float*)d_in[4];
    const float* bias     = (const float*)d_in[5];
    const float* W_out    = (const float*)d_in[6];
    const float* resp_out = (const float*)d_in[7];
    const float* b_out    = (const float*)d_in[8];
    const int*   n_iters  = (const int*)d_in[9];
    float* out = (float*)d_out;
    unsigned short* ws = (unsigned short*)d_ws;

    prep_weights<<<17, 256, 0, stream>>>(W_h, W_out, resp, resp_out, ws);
    fused_net<<<NPIX / 128, 512, 0, stream>>>(x_in, W_in, r_rec, resp, bias,
                                              b_out, n_iters, ws, out);
}

// Round 7
// 54.243 us; speedup vs baseline: 3.6371x; 3.6371x over previous
//
#include <hip/hip_runtime.h>
#include <hip/hip_bf16.h>

#define HID   128
#define PBLK  128
#define NPIX  (256*512)
#define L2E2  2.88539008177792681f   // 2*log2(e)

typedef __attribute__((ext_vector_type(8))) short bf16x8;
typedef __attribute__((ext_vector_type(4))) float f32x4;

#if __has_builtin(__builtin_amdgcn_exp2f)
__device__ inline float fexp2(float x) { return __builtin_amdgcn_exp2f(x); }
#else
__device__ inline float fexp2(float x) { return exp2f(x); }
#endif

__device__ inline unsigned pack2(float a, float b) {
    __hip_bfloat16 lo = __float2bfloat16(a);
    __hip_bfloat16 hi = __float2bfloat16(b);
    unsigned short ul = *reinterpret_cast<unsigned short*>(&lo);
    unsigned short uh = *reinterpret_cast<unsigned short*>(&hi);
    return (unsigned)ul | ((unsigned)uh << 16);
}
__device__ inline float ulo(unsigned u) { union { unsigned u; float f; } v; v.u = u << 16;        return v.f; }
__device__ inline float uhi(unsigned u) { union { unsigned u; float f; } v; v.u = u & 0xffff0000u; return v.f; }

// tanh(z) where u = 2*log2e*z already folded into operands
__device__ inline float actf(float u) {
    float e = fexp2(u);
    return 1.0f - 2.0f * __builtin_amdgcn_rcpf(e + 1.0f);
}

__device__ inline bf16x8 bc(uint4 v) { return __builtin_bit_cast(bf16x8, v); }

__device__ __forceinline__ uint2 quadact(f32x4 a, uint2 rec, float4 bet) {
    float v0 = actf(fmaf(bet.x, ulo(rec.x), a[0]));
    float v1 = actf(fmaf(bet.y, uhi(rec.x), a[1]));
    float v2 = actf(fmaf(bet.z, ulo(rec.y), a[2]));
    float v3 = actf(fmaf(bet.w, uhi(rec.y), a[3]));
    return make_uint2(pack2(v0, v1), pack2(v2, v3));
}

// ---- prologue: W_h / W_out -> frag-ordered bf16 in ws, rows pre-scaled by 2log2e*resp ----
// chunk# = ((lay*4 + rt2)*2 + aidx)*4 + kb ; lane slot l holds
//   Wh[lay][rt2*32+aidx*16+(l&15)][kb*32+(l>>4)*8 ..+8] * (L2E2*resp[lay+1][row])
// W_out chunks (16-row zero-padded, scaled by L2E2*resp_out) at uint4 offset 4096.
__global__ __launch_bounds__(256) void prep_weights(
    const float* __restrict__ W_h, const float* __restrict__ W_out,
    const float* __restrict__ resp, const float* __restrict__ resp_out,
    unsigned short* __restrict__ ws)
{
    int c = blockIdx.x * 256 + threadIdx.x;
    if (c < 4096) {
        int l = c & 63, kb = (c >> 6) & 3, aidx = (c >> 8) & 1, rt2 = (c >> 9) & 3, lay = (c >> 11) & 1;
        int row = rt2 * 32 + aidx * 16 + (l & 15);
        int k   = kb * 32 + (l >> 4) * 8;
        float al = L2E2 * resp[(lay + 1) * HID + row];
        const float* src = W_h + (lay * HID + row) * HID + k;
        float4 f0 = *(const float4*)src, f1 = *(const float4*)(src + 4);
        uint4 v;
        v.x = pack2(al * f0.x, al * f0.y); v.y = pack2(al * f0.z, al * f0.w);
        v.z = pack2(al * f1.x, al * f1.y); v.w = pack2(al * f1.z, al * f1.w);
        *(uint4*)(ws + (size_t)c * 8) = v;
    } else if (c < 4352) {
        int c2 = c - 4096, l = c2 & 63, kb = c2 >> 6;
        int row = l & 15, k = kb * 32 + (l >> 4) * 8;
        uint4 v = {0u, 0u, 0u, 0u};
        if (row < 3) {
            float al = L2E2 * resp_out[row];
            const float* src = W_out + row * HID + k;
            float4 f0 = *(const float4*)src, f1 = *(const float4*)(src + 4);
            v.x = pack2(al * f0.x, al * f0.y); v.y = pack2(al * f0.z, al * f0.w);
            v.z = pack2(al * f1.x, al * f1.y); v.w = pack2(al * f1.z, al * f1.w);
        }
        *(uint4*)(ws + 32768 + (size_t)c2 * 8) = v;
    }
}

// 1024 threads, 16 waves, 128 px/block. W in LDS (vector-copied from ws image),
// 2 barriers/iter. Per-thread state kept to named scalars (anti-spill).
__global__ __launch_bounds__(1024) void fused_net(
    const float* __restrict__ x_in,     // [3][NPIX]
    const float* __restrict__ W_in,     // [128][3]
    const float* __restrict__ r_rec,    // [3][128]
    const float* __restrict__ resp,     // [3][128]
    const float* __restrict__ bias,     // [3][128]
    const float* __restrict__ b_out,    // [3]
    const int*   __restrict__ n_iters_p,
    const unsigned short* __restrict__ wsw,
    float* __restrict__ out)            // [3][NPIX]
{
    __shared__ __align__(16) uint4 Wh_lds[4096];                 // 65536 B, frag-ordered both layers
    __shared__ __align__(16) unsigned short P0s[8 * 4 * 64 * 8]; // 32768 B
    __shared__ __align__(16) unsigned short P1s[8 * 4 * 64 * 8]; // 32768 B
    __shared__ float4 Winp_s[HID];      // {a*w0,a*w1,a*w2,gamma0}, a = L2E2*resp0
    __shared__ float  beta_s[3 * HID];  // L2E2*resp*r_rec
    __shared__ float  gamma_s[2 * HID]; // L2E2*bias layers 1,2
    __shared__ float  gammao_s[16];     // L2E2*b_out zero-padded
    __shared__ float  xs[3 * PBLK];

    const int t = threadIdx.x;
    const int w = t >> 6, l = t & 63;
    const int lr = l & 15, lg = l >> 4;
    const int rt2 = w >> 2;            // row-tile 0..3 (32 rows)
    const int ct  = w & 3;             // px-tile 0..3 (32 px)
    const int pixbase = (int)blockIdx.x * PBLK;
    const int niters = *n_iters_p;
    const uint4* wsU = (const uint4*)wsw;

    // ---- stage: W image (pure vector copy), params, inputs ----
    #pragma unroll
    for (int i = 0; i < 4; ++i) Wh_lds[t + i * 1024] = wsU[t + i * 1024];
    if (t < 3 * HID) beta_s[t] = L2E2 * resp[t] * r_rec[t];
    if (t < 2 * HID) gamma_s[t] = L2E2 * bias[HID + t];
    if (t < HID) {
        float a = L2E2 * resp[t];
        float4 pv;
        pv.x = a * W_in[t * 3 + 0];
        pv.y = a * W_in[t * 3 + 1];
        pv.z = a * W_in[t * 3 + 2];
        pv.w = L2E2 * bias[t];
        Winp_s[t] = pv;
    }
    if (t < 16) gammao_s[t] = (t < 3) ? L2E2 * b_out[t] : 0.0f;
    if (t < 3 * PBLK) xs[t] = x_in[(t >> 7) * NPIX + pixbase + (t & 127)];
    __syncthreads();

    const int p0 = t & 127, hb2 = t >> 7;
    const float x0 = xs[p0], x1 = xs[128 + p0], x2 = xs[256 + p0];

    unsigned rec0[8];
    uint2 rec1_00{0,0}, rec1_01{0,0}, rec1_10{0,0}, rec1_11{0,0};
    uint2 rec2_00{0,0}, rec2_01{0,0}, rec2_10{0,0}, rec2_11{0,0};
    #pragma unroll
    for (int i = 0; i < 8; ++i) rec0[i] = 0u;

    const bf16x8* P0c = (const bf16x8*)P0s;
    const bf16x8* P1c = (const bf16x8*)P1s;
    const uint4* AP0 = Wh_lds + rt2 * 512 + l;          // layer-1 A frags (LDS)
    const uint4* AP1 = Wh_lds + (4 + rt2) * 512 + l;    // layer-2 A frags

    // epilogue param quads (registers; 32 floats total was fine at r5's 88 VGPR)
    const float4 bt1A = *(const float4*)(beta_s + HID + rt2 * 32 + lg * 4);
    const float4 bt1B = *(const float4*)(beta_s + HID + rt2 * 32 + 16 + lg * 4);
    const float4 bt2A = *(const float4*)(beta_s + 2 * HID + rt2 * 32 + lg * 4);
    const float4 bt2B = *(const float4*)(beta_s + 2 * HID + rt2 * 32 + 16 + lg * 4);
    const float4 gm1A = *(const float4*)(gamma_s + rt2 * 32 + lg * 4);
    const float4 gm1B = *(const float4*)(gamma_s + rt2 * 32 + 16 + lg * 4);
    const float4 gm2A = *(const float4*)(gamma_s + HID + rt2 * 32 + lg * 4);
    const float4 gm2B = *(const float4*)(gamma_s + HID + rt2 * 32 + 16 + lg * 4);

    // LDS write offsets (ushort units) for quadrant (mt,nt)
    const int wr00 = (((ct * 2 + 0) * 4 + rt2) * 64 + (0 + (lg >> 1)) * 16 + lr) * 8 + (lg & 1) * 4;
    const int wr01 = (((ct * 2 + 1) * 4 + rt2) * 64 + (0 + (lg >> 1)) * 16 + lr) * 8 + (lg & 1) * 4;
    const int wr10 = (((ct * 2 + 0) * 4 + rt2) * 64 + (2 + (lg >> 1)) * 16 + lr) * 8 + (lg & 1) * 4;
    const int wr11 = (((ct * 2 + 1) * 4 + rt2) * 64 + (2 + (lg >> 1)) * 16 + lr) * 8 + (lg & 1) * 4;

    for (int it = 0; it < niters; ++it) {
        // ---- L0: leaves -> h0 (VALU), frag-ordered write into P0 ----
        #pragma unroll
        for (int s = 0; s < 2; ++s) {
            uint4 ov;
            #pragma unroll
            for (int q = 0; q < 4; ++q) {
                int c = s * 8 + q * 2, h = hb2 * 16 + c;
                float4 wp0 = Winp_s[h], wp1 = Winp_s[h + 1];
                float bet0 = beta_s[h], bet1 = beta_s[h + 1];
                unsigned rp = rec0[s * 4 + q];
                float c1a = fmaf(wp0.x, x0, fmaf(wp0.y, x1, fmaf(wp0.z, x2, wp0.w)));
                float c1b = fmaf(wp1.x, x0, fmaf(wp1.y, x1, fmaf(wp1.z, x2, wp1.w)));
                float v0 = actf(fmaf(bet0, ulo(rp), c1a));
                float v1 = actf(fmaf(bet1, uhi(rp), c1b));
                unsigned pk = pack2(v0, v1);
                rec0[s * 4 + q] = pk;
                if (q == 0) ov.x = pk; else if (q == 1) ov.y = pk;
                else if (q == 2) ov.z = pk; else ov.w = pk;
            }
            int h8 = hb2 * 16 + s * 8;
            int chunk = ((p0 >> 4) * 4 + (h8 >> 5)) * 64 + ((h8 >> 3) & 3) * 16 + (p0 & 15);
            *(uint4*)(P0s + chunk * 8) = ov;
        }
        __syncthreads();

        // ---- layer 1: P0 -> P1 (A from LDS, ds_read feeding MFMA) ----
        {
            const bf16x8* SB = P0c + (ct * 8) * 64 + l;
            f32x4 acc0{gm1A.x, gm1A.y, gm1A.z, gm1A.w};
            f32x4 acc1 = acc0;
            f32x4 acc2{gm1B.x, gm1B.y, gm1B.z, gm1B.w};
            f32x4 acc3 = acc2;
            #pragma unroll
            for (int kb = 0; kb < 4; ++kb) {
                bf16x8 a0 = bc(AP0[kb * 64]);
                bf16x8 a1 = bc(AP0[(4 + kb) * 64]);
                bf16x8 b0 = SB[kb * 64];
                bf16x8 b1 = SB[(4 + kb) * 64];
                acc0 = __builtin_amdgcn_mfma_f32_16x16x32_bf16(a0, b0, acc0, 0, 0, 0);
                acc1 = __builtin_amdgcn_mfma_f32_16x16x32_bf16(a0, b1, acc1, 0, 0, 0);
                acc2 = __builtin_amdgcn_mfma_f32_16x16x32_bf16(a1, b0, acc2, 0, 0, 0);
                acc3 = __builtin_amdgcn_mfma_f32_16x16x32_bf16(a1, b1, acc3, 0, 0, 0);
            }
            rec1_00 = quadact(acc0, rec1_00, bt1A);
            rec1_01 = quadact(acc1, rec1_01, bt1A);
            rec1_10 = quadact(acc2, rec1_10, bt1B);
            rec1_11 = quadact(acc3, rec1_11, bt1B);
            *(uint2*)(P1s + wr00) = rec1_00;
            *(uint2*)(P1s + wr01) = rec1_01;
            *(uint2*)(P1s + wr10) = rec1_10;
            *(uint2*)(P1s + wr11) = rec1_11;
        }
        __syncthreads();

        // ---- layer 2: P1 -> regs (P0 write only on last iter; no barrier otherwise) ----
        {
            const bool last = (it == niters - 1);
            const bf16x8* SB = P1c + (ct * 8) * 64 + l;
            f32x4 acc0{gm2A.x, gm2A.y, gm2A.z, gm2A.w};
            f32x4 acc1 = acc0;
            f32x4 acc2{gm2B.x, gm2B.y, gm2B.z, gm2B.w};
            f32x4 acc3 = acc2;
            #pragma unroll
            for (int kb = 0; kb < 4; ++kb) {
                bf16x8 a0 = bc(AP1[kb * 64]);
                bf16x8 a1 = bc(AP1[(4 + kb) * 64]);
                bf16x8 b0 = SB[kb * 64];
                bf16x8 b1 = SB[(4 + kb) * 64];
                acc0 = __builtin_amdgcn_mfma_f32_16x16x32_bf16(a0, b0, acc0, 0, 0, 0);
                acc1 = __builtin_amdgcn_mfma_f32_16x16x32_bf16(a0, b1, acc1, 0, 0, 0);
                acc2 = __builtin_amdgcn_mfma_f32_16x16x32_bf16(a1, b0, acc2, 0, 0, 0);
                acc3 = __builtin_amdgcn_mfma_f32_16x16x32_bf16(a1, b1, acc3, 0, 0, 0);
            }
            rec2_00 = quadact(acc0, rec2_00, bt2A);
            rec2_01 = quadact(acc1, rec2_01, bt2A);
            rec2_10 = quadact(acc2, rec2_10, bt2B);
            rec2_11 = quadact(acc3, rec2_11, bt2B);
            if (last) {
                *(uint2*)(P0s + wr00) = rec2_00;
                *(uint2*)(P0s + wr01) = rec2_01;
                *(uint2*)(P0s + wr10) = rec2_10;
                *(uint2*)(P0s + wr11) = rec2_11;
            }
        }
    }
    __syncthreads();

    // ---- output layer: waves 0..7, one 16-px group each; W_out from ws (L2-hot) ----
    if (w < 8) {
        float4 go = *(const float4*)(gammao_s + lg * 4);
        f32x4 oacc{go.x, go.y, go.z, go.w};
        const uint4* OA = wsU + 4096 + l;
        const bf16x8* OB = P0c + (w * 4) * 64 + l;
        oacc = __builtin_amdgcn_mfma_f32_16x16x32_bf16(bc(OA[0 * 64]), OB[0 * 64], oacc, 0, 0, 0);
        oacc = __builtin_amdgcn_mfma_f32_16x16x32_bf16(bc(OA[1 * 64]), OB[1 * 64], oacc, 0, 0, 0);
        oacc = __builtin_amdgcn_mfma_f32_16x16x32_bf16(bc(OA[2 * 64]), OB[2 * 64], oacc, 0, 0, 0);
        oacc = __builtin_amdgcn_mfma_f32_16x16x32_bf16(bc(OA[3 * 64]), OB[3 * 64], oacc, 0, 0, 0);
        int p = pixbase + w * 16 + lr;
        if (lg == 0) {
            out[0 * NPIX + p] = actf(oacc[0]);
            out[1 * NPIX + p] = actf(oacc[1]);
            out[2 * NPIX + p] = actf(oacc[2]);
        }
    }
}

extern "C" void kernel_launch(void* const* d_in, const int* in_sizes, int n_in,
                              void* d_out, int out_size, void* d_ws, size_t ws_size,
                              hipStream_t stream) {
    const float* x_in     = (const float*)d_in[0];
    const float* W_in     = (const float*)d_in[1];
    const float* W_h      = (const float*)d_in[2];
    const float* r_rec    = (const float*)d_in[3];
    const float* resp     = (const float*)d_in[4];
    const float* bias     = (const float*)d_in[5];
    const float* W_out    = (const float*)d_in[6];
    const float* resp_out = (const float*)d_in[7];
    const float* b_out    = (const float*)d_in[8];
    const int*   n_iters  = (const int*)d_in[9];
    float* out = (float*)d_out;
    unsigned short* ws = (unsigned short*)d_ws;

    prep_weights<<<17, 256, 0, stream>>>(W_h, W_out, resp, resp_out, ws);
    fused_net<<<NPIX / PBLK, 1024, 0, stream>>>(x_in, W_in, r_rec, resp, bias,
                                                b_out, n_iters, ws, out);
}